// Round 10
// baseline (773.192 us; speedup 1.0000x reference)
//
#include <hip/hip_runtime.h>

#define NBQ 12544
#define DM  256
#define MM  2048

typedef __attribute__((ext_vector_type(8)))  __bf16 bf16x8;
typedef __attribute__((ext_vector_type(4)))  float  floatx4;

__device__ __forceinline__ ushort f2bf(float x) {
    unsigned u = __float_as_uint(x);
    u += 0x7fffu + ((u >> 16) & 1u);   // RNE
    return (ushort)(u >> 16);
}
__device__ __forceinline__ float bf2f(ushort h) {
    return __uint_as_float(((unsigned)h) << 16);
}

// ---------------- ALL projections in one launch: C = A(fp32) * W(fp32)^T, bf16 out ----
__global__ __launch_bounds__(256) void gemm_proj_all(
    const float* __restrict__ x,      const float* __restrict__ ch_mem,
    const float* __restrict__ ch_wq,  const float* __restrict__ ch_wk,
    const float* __restrict__ ch_wv,  const float* __restrict__ sp_mem,
    const float* __restrict__ sp_wq,  const float* __restrict__ sp_wk,
    const float* __restrict__ sp_wv,
    ushort* __restrict__ Qb,  ushort* __restrict__ QFb,
    ushort* __restrict__ Kb,  ushort* __restrict__ KFb,
    ushort* __restrict__ Vtb, ushort* __restrict__ VFtb)
{
    __shared__ ushort As[64][72];
    __shared__ ushort Ws[64][72];

    int bid = blockIdx.x;
    const float* A; const float* W; ushort* C; int nrows, trans;
    if (bid < 1568) {
        if (bid < 784) { A = x; W = ch_wq; C = Qb; }
        else           { A = x; W = sp_wq; C = QFb; bid -= 784; }
        nrows = NBQ; trans = 0;
    } else if (bid < 1824) {
        if (bid < 1696) { A = ch_mem; W = ch_wk; C = Kb;  bid -= 1568; }
        else            { A = sp_mem; W = sp_wk; C = KFb; bid -= 1696; }
        nrows = MM; trans = 0;
    } else {
        if (bid < 1952) { A = ch_mem; W = ch_wv; C = Vtb;  bid -= 1824; }
        else            { A = sp_mem; W = sp_wv; C = VFtb; bid -= 1952; }
        nrows = MM; trans = 1;
    }
    const int r0 = (bid >> 2) * 64;
    const int c0 = (bid & 3) * 64;

    const int tid  = threadIdx.x;
    const int wv   = tid >> 6;
    const int lane = tid & 63;
    const int quad = lane >> 4;
    const int l16  = lane & 15;
    const int rw = (wv & 1) * 32;
    const int cw = (wv >> 1) * 32;

    floatx4 acc[2][2];
    #pragma unroll
    for (int i = 0; i < 2; ++i)
        #pragma unroll
        for (int j = 0; j < 2; ++j)
            acc[i][j] = (floatx4){0.f, 0.f, 0.f, 0.f};

    for (int d0 = 0; d0 < 256; d0 += 64) {
        __syncthreads();
        #pragma unroll
        for (int it = 0; it < 4; ++it) {
            int idx = tid + it * 256;
            int r = idx >> 4, c4 = (idx & 15) * 4;
            float4 a4 = *(const float4*)(A + (size_t)(r0 + r) * 256 + d0 + c4);
            float4 w4 = *(const float4*)(W + (size_t)(c0 + r) * 256 + d0 + c4);
            ushort4 ab, wb;
            ab.x = f2bf(a4.x); ab.y = f2bf(a4.y); ab.z = f2bf(a4.z); ab.w = f2bf(a4.w);
            wb.x = f2bf(w4.x); wb.y = f2bf(w4.y); wb.z = f2bf(w4.z); wb.w = f2bf(w4.w);
            *(ushort4*)&As[r][c4] = ab;
            *(ushort4*)&Ws[r][c4] = wb;
        }
        __syncthreads();
        #pragma unroll
        for (int kk = 0; kk < 64; kk += 32) {
            bf16x8 aA0 = *(const bf16x8*)&As[rw + l16][kk + quad * 8];
            bf16x8 aA1 = *(const bf16x8*)&As[rw + 16 + l16][kk + quad * 8];
            bf16x8 bW0 = *(const bf16x8*)&Ws[cw + l16][kk + quad * 8];
            bf16x8 bW1 = *(const bf16x8*)&Ws[cw + 16 + l16][kk + quad * 8];
            acc[0][0] = __builtin_amdgcn_mfma_f32_16x16x32_bf16(aA0, bW0, acc[0][0], 0, 0, 0);
            acc[0][1] = __builtin_amdgcn_mfma_f32_16x16x32_bf16(aA0, bW1, acc[0][1], 0, 0, 0);
            acc[1][0] = __builtin_amdgcn_mfma_f32_16x16x32_bf16(aA1, bW0, acc[1][0], 0, 0, 0);
            acc[1][1] = __builtin_amdgcn_mfma_f32_16x16x32_bf16(aA1, bW1, acc[1][1], 0, 0, 0);
        }
    }

    if (!trans) {
        #pragma unroll
        for (int ag = 0; ag < 2; ++ag)
            #pragma unroll
            for (int cg = 0; cg < 2; ++cg)
                #pragma unroll
                for (int i = 0; i < 4; ++i)
                    C[(size_t)(r0 + rw + ag * 16 + quad * 4 + i) * 256
                      + c0 + cw + cg * 16 + l16] = f2bf(acc[ag][cg][i]);
    } else {
        __syncthreads();
        #pragma unroll
        for (int ag = 0; ag < 2; ++ag)
            #pragma unroll
            for (int cg = 0; cg < 2; ++cg)
                #pragma unroll
                for (int i = 0; i < 4; ++i)
                    Ws[cw + cg * 16 + l16][rw + ag * 16 + quad * 4 + i] = f2bf(acc[ag][cg][i]);
        __syncthreads();
        const int col = tid >> 2;
        const int seg = (tid & 3) * 16;
        #pragma unroll
        for (int j = 0; j < 2; ++j)
            *(uint4*)(C + (size_t)(c0 + col) * nrows + r0 + seg + j * 8) =
                *(const uint4*)&Ws[col][seg + j * 8];
    }
}

// ---------------- row stats (QF rows then KF rows), one launch ----------------
__global__ __launch_bounds__(256) void row_stats_all(
    const ushort* __restrict__ QFb, const ushort* __restrict__ KFb,
    float* __restrict__ qm, float* __restrict__ qv,
    float* __restrict__ km, float* __restrict__ kv)
{
    const int rt   = blockIdx.x * 4 + (threadIdx.x >> 6);
    const int lane = threadIdx.x & 63;
    const ushort* X; float* mean; float* var; int row;
    if (rt < NBQ) { X = QFb; mean = qm; var = qv; row = rt; }
    else          { X = KFb; mean = km; var = kv; row = rt - NBQ; }
    ushort4 u = *(const ushort4*)(X + (size_t)row * 256 + lane * 4);
    float a = bf2f(u.x), b = bf2f(u.y), c = bf2f(u.z), d = bf2f(u.w);
    float s  = a + b + c + d;
    float ss = a * a + b * b + c * c + d * d;
    #pragma unroll
    for (int off = 32; off > 0; off >>= 1) {
        s  += __shfl_down(s, off);
        ss += __shfl_down(ss, off);
    }
    if (lane == 0) {
        float m = s * (1.f / 256.f);
        mean[row] = m;
        var[row]  = (ss - 256.f * m * m) * (1.f / 255.f);
    }
}

// ---------------- fused attention: branch-per-block, 32q, register-prefetch ---------
// grid 784 = 392 q-blocks x 2 branches; LDS 37,888 B -> 3 blocks/CU (768 slots) ->
// ~1 balanced round, lockstep key walk (L2 reuse). Software pipeline: next tile's
// K/V global loads issued into regs during current tile's score/epi/PV.
// All LDS row strides = 4 mod 32 dwords (K 132, VV 36, P 18) -> phase-uniform banks.
// VV folded: row r in [0,128) holds dims r (cols 0..31) and r+128 (cols 32..63).
__global__ __launch_bounds__(256, 3) void fused_attn_32q(
    const ushort* __restrict__ Qb,  const ushort* __restrict__ QFb,
    const ushort* __restrict__ Kb,  const ushort* __restrict__ KFb,
    const ushort* __restrict__ Vtb, const ushort* __restrict__ VFtb,
    const float* __restrict__ qm_, const float* __restrict__ qv_,
    const float* __restrict__ km_, const float* __restrict__ kv_,
    float* __restrict__ out)
{
    __shared__ ushort K_lds[32][264];   // 528B stride
    __shared__ ushort VV_lds[128][72];  // folded V, 144B stride
    __shared__ ushort P_lds[32][36];    // 72B stride (quad-disjoint octets)
    __shared__ float  denbuf[2][32];
    // total LDS = 16896 + 18432 + 2304 + 256 = 37888 B -> 3 blocks/CU

    const int tid  = threadIdx.x;
    const int wv   = tid >> 6;
    const int lane = tid & 63;
    const int quad = lane >> 4;
    const int l16  = lane & 15;
    const int qh   = wv & 1;    // score q-half
    const int kh   = wv >> 1;   // score k-half

    const bool spatial = (blockIdx.x >= 392);
    const int q0 = (spatial ? (int)blockIdx.x - 392 : (int)blockIdx.x) * 32;
    const ushort* Qp = spatial ? QFb  : Qb;
    const ushort* Kp = spatial ? KFb  : Kb;
    const ushort* Vp = spatial ? VFtb : Vtb;

    // per-thread staging coordinates (4 chunks each for K and V)
    int kr[4], kc8[4], vrow[4], vcol[4];
    size_t vgoff[4];
    #pragma unroll
    for (int it = 0; it < 4; ++it) {
        int idx = tid + it * 256;
        kr[it]  = idx >> 5;            // K row 0..31
        kc8[it] = (idx & 31) * 8;      // K col chunk
        int r  = idx >> 3;             // VV row 0..127
        int c  = idx & 7;
        int dhi = c >> 2, kc = c & 3;
        vrow[it]  = r;
        vcol[it]  = dhi * 32 + kc * 8;
        vgoff[it] = (size_t)(r + dhi * 128) * MM + kc * 8;
    }

    // Q A-fragments in registers: A[m=l16][k=quad*8+j], K=256 -> 8 frags
    bf16x8 aQ[8];
    {
        const ushort* qp = Qp + (size_t)(q0 + qh * 16 + l16) * DM + quad * 8;
        #pragma unroll
        for (int s = 0; s < 8; ++s) aQ[s] = *(const bf16x8*)(qp + s * 32);
    }
    float qmr[4], qvr[4];
    if (spatial) {
        #pragma unroll
        for (int r = 0; r < 4; ++r) {
            int row = q0 + qh * 16 + quad * 4 + r;
            qmr[r] = qm_[row]; qvr[r] = qv_[row];
        }
    }

    floatx4 accO[2][4];    // [q-half][d-subtile], d-quarter = wv*64
    #pragma unroll
    for (int a = 0; a < 2; ++a)
        #pragma unroll
        for (int b = 0; b < 4; ++b)
            accO[a][b] = (floatx4){0.f, 0.f, 0.f, 0.f};
    float den_r[4] = {0.f, 0.f, 0.f, 0.f};

    // prefetch tile 0 into registers
    uint4 kreg[4], vreg[4];
    #pragma unroll
    for (int it = 0; it < 4; ++it) {
        kreg[it] = *(const uint4*)(Kp + (size_t)kr[it] * DM + kc8[it]);
        vreg[it] = *(const uint4*)(Vp + vgoff[it]);
    }

    for (int kt = 0; kt < MM; kt += 32) {
        __syncthreads();  // prev tile's K/VV/P reads done
        #pragma unroll
        for (int it = 0; it < 4; ++it) {
            *(uint4*)&K_lds[kr[it]][kc8[it]]   = kreg[it];
            *(uint4*)&VV_lds[vrow[it]][vcol[it]] = vreg[it];
        }
        __syncthreads();

        // issue next tile's global loads (overlap with compute below)
        if (kt + 32 < MM) {
            #pragma unroll
            for (int it = 0; it < 4; ++it) {
                kreg[it] = *(const uint4*)(Kp + (size_t)(kt + 32 + kr[it]) * DM + kc8[it]);
                vreg[it] = *(const uint4*)(Vp + vgoff[it] + kt + 32);
            }
        }

        // ---- scores: 16q x 16k per wave, K=256 ----
        floatx4 S = (floatx4){0.f, 0.f, 0.f, 0.f};
        #pragma unroll
        for (int s = 0; s < 8; ++s) {
            bf16x8 bK = *(const bf16x8*)&K_lds[kh * 16 + l16][s * 32 + quad * 8];
            S = __builtin_amdgcn_mfma_f32_16x16x32_bf16(aQ[s], bK, S, 0, 0, 0);
        }
        // ---- epilogue -> P (bf16) + den partials. C-layout: col=l16(k), row=quad*4+r
        {
            int kcol = kt + kh * 16 + l16;
            float kmv = 0.f, kvv = 0.f;
            if (spatial) { kmv = km_[kcol]; kvv = kv_[kcol]; }
            #pragma unroll
            for (int r = 0; r < 4; ++r) {
                float p;
                if (!spatial) {
                    p = __expf(S[r] * 0.0625f);
                } else {
                    float mp  = qmr[r] * kmv;
                    float cov = (S[r] - 256.f * mp) * (1.f / 255.f);
                    float num = (2.f * mp + 0.01f) * (2.f * cov + 0.03f);
                    float den = (qmr[r] * qmr[r] + kmv * kmv + 0.01f) * (qvr[r] + kvv + 0.03f);
                    p = __expf(num / (den + 1e-8f));
                }
                P_lds[qh * 16 + quad * 4 + r][kh * 16 + l16] = f2bf(p);
                den_r[r] += p;
            }
        }
        __syncthreads();

        // ---- PV: wave = d-quarter (wv*64), A = P (both q-halves), K=32 ----
        bf16x8 aP0 = *(const bf16x8*)&P_lds[l16][quad * 8];
        bf16x8 aP1 = *(const bf16x8*)&P_lds[16 + l16][quad * 8];
        #pragma unroll
        for (int ds = 0; ds < 4; ++ds) {
            int d = wv * 64 + ds * 16 + l16;
            bf16x8 bV = *(const bf16x8*)&VV_lds[d & 127][(d >> 7) * 32 + quad * 8];
            accO[0][ds] = __builtin_amdgcn_mfma_f32_16x16x32_bf16(aP0, bV, accO[0][ds], 0, 0, 0);
            accO[1][ds] = __builtin_amdgcn_mfma_f32_16x16x32_bf16(aP1, bV, accO[1][ds], 0, 0, 0);
        }
    }

    // ---- denominators: reduce over the wave's 16 k-cols, combine k-halves via LDS --
    #pragma unroll
    for (int r = 0; r < 4; ++r)
        #pragma unroll
        for (int m = 1; m < 16; m <<= 1)
            den_r[r] += __shfl_xor(den_r[r], m, 64);
    if (l16 == 0) {
        #pragma unroll
        for (int r = 0; r < 4; ++r)
            denbuf[kh][qh * 16 + quad * 4 + r] = den_r[r];
    }
    __syncthreads();

    // ---- output: normalize + atomicAdd combine (2 adds/element, deterministic) ----
    #pragma unroll
    for (int qt = 0; qt < 2; ++qt) {
        #pragma unroll
        for (int r = 0; r < 4; ++r) {
            int rloc = qt * 16 + quad * 4 + r;
            float rden = 1.f / (denbuf[0][rloc] + denbuf[1][rloc]);
            #pragma unroll
            for (int ds = 0; ds < 4; ++ds)
                atomicAdd(out + (size_t)(q0 + rloc) * DM + wv * 64 + ds * 16 + l16,
                          accO[qt][ds][r] * rden);
        }
    }
}

extern "C" void kernel_launch(void* const* d_in, const int* in_sizes, int n_in,
                              void* d_out, int out_size, void* d_ws, size_t ws_size,
                              hipStream_t stream)
{
    const float* x      = (const float*)d_in[0];
    const float* ch_mem = (const float*)d_in[1];
    const float* ch_wq  = (const float*)d_in[2];
    const float* ch_wk  = (const float*)d_in[3];
    const float* ch_wv  = (const float*)d_in[4];
    const float* sp_mem = (const float*)d_in[5];
    const float* sp_wq  = (const float*)d_in[6];
    const float* sp_wk  = (const float*)d_in[7];
    const float* sp_wv  = (const float*)d_in[8];
    float* out = (float*)d_out;

    ushort* Qb   = (ushort*)d_ws;                 // [12544][256]
    ushort* QFb  = Qb   + (size_t)NBQ * DM;
    ushort* Kb   = QFb  + (size_t)NBQ * DM;       // [2048][256]
    ushort* KFb  = Kb   + (size_t)MM * DM;
    ushort* Vtb  = KFb  + (size_t)MM * DM;        // [256][2048] transposed
    ushort* VFtb = Vtb  + (size_t)MM * DM;
    float*  qm   = (float*)(VFtb + (size_t)MM * DM);
    float*  qv   = qm + NBQ;
    float*  km   = qv + NBQ;
    float*  kv   = km + MM;

    hipMemsetAsync(out, 0, (size_t)NBQ * DM * sizeof(float), stream);

    dim3 blk(256);
    gemm_proj_all<<<dim3(2080), blk, 0, stream>>>(
        x, ch_mem, ch_wq, ch_wk, ch_wv, sp_mem, sp_wq, sp_wk, sp_wv,
        Qb, QFb, Kb, KFb, Vtb, VFtb);
    row_stats_all<<<dim3((NBQ + MM) / 4), blk, 0, stream>>>(QFb, KFb, qm, qv, km, kv);
    fused_attn_32q<<<dim3(784), blk, 0, stream>>>(
        Qb, QFb, Kb, KFb, Vtb, VFtb, qm, qv, km, kv, out);
}

// Round 11
// 423.595 us; speedup vs baseline: 1.8253x; 1.8253x over previous
//
#include <hip/hip_runtime.h>

#define NBQ 12544
#define DM  256
#define MM  2048

typedef __attribute__((ext_vector_type(8)))  __bf16 bf16x8;
typedef __attribute__((ext_vector_type(4)))  float  floatx4;

__device__ __forceinline__ ushort f2bf(float x) {
    unsigned u = __float_as_uint(x);
    u += 0x7fffu + ((u >> 16) & 1u);   // RNE
    return (ushort)(u >> 16);
}
__device__ __forceinline__ float bf2f(ushort h) {
    return __uint_as_float(((unsigned)h) << 16);
}

// ---------- projections, weight-pairs folded: each block computes A*W1^T and A*W2^T --
// bid <  784: A=x      -> Qb (W1=ch_wq, no-trans) + QFb (W2=sp_wq, no-trans)
// 784..912 : A=ch_mem -> Kb (W1=ch_wk, no-trans) + Vtb (W2=ch_wv, TRANS)
// 912..1040: A=sp_mem -> KFb(W1=sp_wk, no-trans) + VFtb(W2=sp_wv, TRANS)
__global__ __launch_bounds__(256) void gemm_proj_all(
    const float* __restrict__ x,      const float* __restrict__ ch_mem,
    const float* __restrict__ ch_wq,  const float* __restrict__ ch_wk,
    const float* __restrict__ ch_wv,  const float* __restrict__ sp_mem,
    const float* __restrict__ sp_wq,  const float* __restrict__ sp_wk,
    const float* __restrict__ sp_wv,
    ushort* __restrict__ Qb,  ushort* __restrict__ QFb,
    ushort* __restrict__ Kb,  ushort* __restrict__ KFb,
    ushort* __restrict__ Vtb, ushort* __restrict__ VFtb)
{
    __shared__ ushort As[64][72];
    __shared__ ushort W1s[64][72];
    __shared__ ushort W2s[64][72];   // also transpose scratch for the trans2 path

    int bid = blockIdx.x;
    const float* A; const float* W1; const float* W2;
    ushort* C1; ushort* C2; int nrows, trans2;
    if (bid < 784) {
        A = x; W1 = ch_wq; W2 = sp_wq; C1 = Qb; C2 = QFb; nrows = NBQ; trans2 = 0;
    } else if (bid < 912) {
        A = ch_mem; W1 = ch_wk; W2 = ch_wv; C1 = Kb; C2 = Vtb;
        nrows = MM; trans2 = 1; bid -= 784;
    } else {
        A = sp_mem; W1 = sp_wk; W2 = sp_wv; C1 = KFb; C2 = VFtb;
        nrows = MM; trans2 = 1; bid -= 912;
    }
    const int r0 = (bid >> 2) * 64;
    const int c0 = (bid & 3) * 64;

    const int tid  = threadIdx.x;
    const int wv   = tid >> 6;
    const int lane = tid & 63;
    const int quad = lane >> 4;
    const int l16  = lane & 15;
    const int rw = (wv & 1) * 32;
    const int cw = (wv >> 1) * 32;

    floatx4 acc1[2][2], acc2[2][2];
    #pragma unroll
    for (int i = 0; i < 2; ++i)
        #pragma unroll
        for (int j = 0; j < 2; ++j) {
            acc1[i][j] = (floatx4){0.f, 0.f, 0.f, 0.f};
            acc2[i][j] = (floatx4){0.f, 0.f, 0.f, 0.f};
        }

    for (int d0 = 0; d0 < 256; d0 += 64) {
        __syncthreads();
        #pragma unroll
        for (int it = 0; it < 4; ++it) {
            int idx = tid + it * 256;
            int r = idx >> 4, c4 = (idx & 15) * 4;
            float4 a4 = *(const float4*)(A  + (size_t)(r0 + r) * 256 + d0 + c4);
            float4 w14 = *(const float4*)(W1 + (size_t)(c0 + r) * 256 + d0 + c4);
            float4 w24 = *(const float4*)(W2 + (size_t)(c0 + r) * 256 + d0 + c4);
            ushort4 ab, w1b, w2b;
            ab.x = f2bf(a4.x);  ab.y = f2bf(a4.y);  ab.z = f2bf(a4.z);  ab.w = f2bf(a4.w);
            w1b.x = f2bf(w14.x); w1b.y = f2bf(w14.y); w1b.z = f2bf(w14.z); w1b.w = f2bf(w14.w);
            w2b.x = f2bf(w24.x); w2b.y = f2bf(w24.y); w2b.z = f2bf(w24.z); w2b.w = f2bf(w24.w);
            *(ushort4*)&As[r][c4]  = ab;
            *(ushort4*)&W1s[r][c4] = w1b;
            *(ushort4*)&W2s[r][c4] = w2b;
        }
        __syncthreads();
        #pragma unroll
        for (int kk = 0; kk < 64; kk += 32) {
            bf16x8 aA0 = *(const bf16x8*)&As[rw + l16][kk + quad * 8];
            bf16x8 aA1 = *(const bf16x8*)&As[rw + 16 + l16][kk + quad * 8];
            bf16x8 b10 = *(const bf16x8*)&W1s[cw + l16][kk + quad * 8];
            bf16x8 b11 = *(const bf16x8*)&W1s[cw + 16 + l16][kk + quad * 8];
            bf16x8 b20 = *(const bf16x8*)&W2s[cw + l16][kk + quad * 8];
            bf16x8 b21 = *(const bf16x8*)&W2s[cw + 16 + l16][kk + quad * 8];
            acc1[0][0] = __builtin_amdgcn_mfma_f32_16x16x32_bf16(aA0, b10, acc1[0][0], 0, 0, 0);
            acc1[0][1] = __builtin_amdgcn_mfma_f32_16x16x32_bf16(aA0, b11, acc1[0][1], 0, 0, 0);
            acc1[1][0] = __builtin_amdgcn_mfma_f32_16x16x32_bf16(aA1, b10, acc1[1][0], 0, 0, 0);
            acc1[1][1] = __builtin_amdgcn_mfma_f32_16x16x32_bf16(aA1, b11, acc1[1][1], 0, 0, 0);
            acc2[0][0] = __builtin_amdgcn_mfma_f32_16x16x32_bf16(aA0, b20, acc2[0][0], 0, 0, 0);
            acc2[0][1] = __builtin_amdgcn_mfma_f32_16x16x32_bf16(aA0, b21, acc2[0][1], 0, 0, 0);
            acc2[1][0] = __builtin_amdgcn_mfma_f32_16x16x32_bf16(aA1, b20, acc2[1][0], 0, 0, 0);
            acc2[1][1] = __builtin_amdgcn_mfma_f32_16x16x32_bf16(aA1, b21, acc2[1][1], 0, 0, 0);
        }
    }

    // C1: always row-major
    #pragma unroll
    for (int ag = 0; ag < 2; ++ag)
        #pragma unroll
        for (int cg = 0; cg < 2; ++cg)
            #pragma unroll
            for (int i = 0; i < 4; ++i)
                C1[(size_t)(r0 + rw + ag * 16 + quad * 4 + i) * 256
                   + c0 + cw + cg * 16 + l16] = f2bf(acc1[ag][cg][i]);

    if (!trans2) {
        #pragma unroll
        for (int ag = 0; ag < 2; ++ag)
            #pragma unroll
            for (int cg = 0; cg < 2; ++cg)
                #pragma unroll
                for (int i = 0; i < 4; ++i)
                    C2[(size_t)(r0 + rw + ag * 16 + quad * 4 + i) * 256
                       + c0 + cw + cg * 16 + l16] = f2bf(acc2[ag][cg][i]);
    } else {
        __syncthreads();  // all waves done reading W2s
        #pragma unroll
        for (int ag = 0; ag < 2; ++ag)
            #pragma unroll
            for (int cg = 0; cg < 2; ++cg)
                #pragma unroll
                for (int i = 0; i < 4; ++i)
                    W2s[cw + cg * 16 + l16][rw + ag * 16 + quad * 4 + i] = f2bf(acc2[ag][cg][i]);
        __syncthreads();
        const int col = tid >> 2;
        const int seg = (tid & 3) * 16;
        #pragma unroll
        for (int j = 0; j < 2; ++j)
            *(uint4*)(C2 + (size_t)(c0 + col) * nrows + r0 + seg + j * 8) =
                *(const uint4*)&W2s[col][seg + j * 8];
    }
}

// ---------------- row stats (QF rows then KF rows), one launch ----------------
__global__ __launch_bounds__(256) void row_stats_all(
    const ushort* __restrict__ QFb, const ushort* __restrict__ KFb,
    float* __restrict__ qm, float* __restrict__ qv,
    float* __restrict__ km, float* __restrict__ kv)
{
    const int rt   = blockIdx.x * 4 + (threadIdx.x >> 6);
    const int lane = threadIdx.x & 63;
    const ushort* X; float* mean; float* var; int row;
    if (rt < NBQ) { X = QFb; mean = qm; var = qv; row = rt; }
    else          { X = KFb; mean = km; var = kv; row = rt - NBQ; }
    ushort4 u = *(const ushort4*)(X + (size_t)row * 256 + lane * 4);
    float a = bf2f(u.x), b = bf2f(u.y), c = bf2f(u.z), d = bf2f(u.w);
    float s  = a + b + c + d;
    float ss = a * a + b * b + c * c + d * d;
    #pragma unroll
    for (int off = 32; off > 0; off >>= 1) {
        s  += __shfl_down(s, off);
        ss += __shfl_down(ss, off);
    }
    if (lane == 0) {
        float m = s * (1.f / 256.f);
        mean[row] = m;
        var[row]  = (ss - 256.f * m * m) * (1.f / 255.f);
    }
}

// ---------------- fused dual attention (r9 structure) + folded conflict-free V ------
// Block: 32 queries, 4 waves, BOTH branches (K/V staging amortized over 2 branches).
// Wave w: qsel=w&1 (score q-half / PV q-half), ksel=w>>1 (score k-half / PV d-half).
// VV folded: row r in [0,128) holds dims r (cols 0..31) and r+128 (cols 32..63);
// row stride 36 dwords = 4 mod 32 -> staging writes and PV b128 reads are
// phase-uniform (r10-validated: conflicts halved when Vt stride-20 was removed).
__global__ __launch_bounds__(256, 2) void fused_attn_mfma(
    const ushort* __restrict__ Qb,  const ushort* __restrict__ QFb,
    const ushort* __restrict__ Kb,  const ushort* __restrict__ KFb,
    const ushort* __restrict__ Vtb, const ushort* __restrict__ VFtb,
    const float* __restrict__ qm_, const float* __restrict__ qv_,
    const float* __restrict__ km_, const float* __restrict__ kv_,
    float* __restrict__ out)
{
    __shared__ ushort K_lds[32][264];    // 528B stride (132 dw = 4 mod 32) -> uniform
    __shared__ ushort KF_lds[32][264];
    __shared__ ushort VV_c[128][72];     // folded ch-V, 144B stride (36 dw = 4 mod 32)
    __shared__ ushort VV_s[128][72];     // folded sp-V
    __shared__ ushort P_lds[2][32][36];  // 72B stride (quad-disjoint octets)
    // total LDS = 2*16896 + 2*18432 + 4608 = 75264 B -> 2 blocks/CU

    const int tid  = threadIdx.x;
    const int wv   = tid >> 6;
    const int lane = tid & 63;
    const int quad = lane >> 4;
    const int l16  = lane & 15;
    const int qsel = wv & 1;
    const int ksel = wv >> 1;
    const int q0   = blockIdx.x * 32;

    // Q A-fragments in registers for the whole key loop
    bf16x8 aQ[8], aQF[8];
    {
        const ushort* qp  = Qb  + (size_t)(q0 + qsel * 16 + l16) * DM + quad * 8;
        const ushort* qfp = QFb + (size_t)(q0 + qsel * 16 + l16) * DM + quad * 8;
        #pragma unroll
        for (int s = 0; s < 8; ++s) {
            aQ[s]  = *(const bf16x8*)(qp  + s * 32);
            aQF[s] = *(const bf16x8*)(qfp + s * 32);
        }
    }
    float qmv[4], qvv[4];
    #pragma unroll
    for (int r = 0; r < 4; ++r) {
        int qg = q0 + qsel * 16 + quad * 4 + r;
        qmv[r] = qm_[qg]; qvv[r] = qv_[qg];
    }

    floatx4 acc_c[8], acc_s[8];
    #pragma unroll
    for (int t = 0; t < 8; ++t) {
        acc_c[t] = (floatx4){0.f, 0.f, 0.f, 0.f};
        acc_s[t] = (floatx4){0.f, 0.f, 0.f, 0.f};
    }
    float denc_r[4] = {0.f, 0.f, 0.f, 0.f};
    float dens_r[4] = {0.f, 0.f, 0.f, 0.f};

    for (int kt = 0; kt < MM; kt += 32) {
        __syncthreads();  // previous tile's LDS fully consumed
        // stage K/KF (32 x 256): 1024 uint4-chunks = 32 rows x 32 chunks
        #pragma unroll
        for (int it = 0; it < 4; ++it) {
            int idx = tid + it * 256;
            int r = idx >> 5, c8 = (idx & 31) * 8;
            *(uint4*)&K_lds[r][c8]  = *(const uint4*)(Kb  + (size_t)(kt + r) * DM + c8);
            *(uint4*)&KF_lds[r][c8] = *(const uint4*)(KFb + (size_t)(kt + r) * DM + c8);
        }
        // stage VV (folded): 1024 chunks = 128 rows x 8 chunks (2 d-halves x 4 key-chunks)
        #pragma unroll
        for (int it = 0; it < 4; ++it) {
            int idx = tid + it * 256;
            int r = idx >> 3, c = idx & 7;
            int dhi = c >> 2, kc = c & 3;
            int col = dhi * 32 + kc * 8;
            size_t g = (size_t)(r + dhi * 128) * MM + kt + kc * 8;
            *(uint4*)&VV_c[r][col] = *(const uint4*)(Vtb  + g);
            *(uint4*)&VV_s[r][col] = *(const uint4*)(VFtb + g);
        }
        __syncthreads();

        // ---- scores: 16q x 16k per wave, both branches ----
        floatx4 sc = (floatx4){0.f, 0.f, 0.f, 0.f};
        floatx4 sd = (floatx4){0.f, 0.f, 0.f, 0.f};
        #pragma unroll
        for (int s = 0; s < 8; ++s) {
            bf16x8 bK  = *(const bf16x8*)&K_lds[ksel * 16 + l16][s * 32 + quad * 8];
            bf16x8 bKF = *(const bf16x8*)&KF_lds[ksel * 16 + l16][s * 32 + quad * 8];
            sc = __builtin_amdgcn_mfma_f32_16x16x32_bf16(aQ[s],  bK,  sc, 0, 0, 0);
            sd = __builtin_amdgcn_mfma_f32_16x16x32_bf16(aQF[s], bKF, sd, 0, 0, 0);
        }
        // ---- epilogue: exp(score/16), SSIM -> P (bf16), denominator partials ----
        {
            float kmv = km_[kt + ksel * 16 + l16];
            float kvv = kv_[kt + ksel * 16 + l16];
            #pragma unroll
            for (int r = 0; r < 4; ++r) {
                float p1  = __expf(sc[r] * 0.0625f);
                float mp  = qmv[r] * kmv;
                float cov = (sd[r] - 256.f * mp) * (1.f / 255.f);
                float num = (2.f * mp + 0.01f) * (2.f * cov + 0.03f);
                float den = (qmv[r] * qmv[r] + kmv * kmv + 0.01f) * (qvv[r] + kvv + 0.03f);
                float p2  = __expf(num / (den + 1e-8f));
                P_lds[0][qsel * 16 + quad * 4 + r][ksel * 16 + l16] = f2bf(p1);
                P_lds[1][qsel * 16 + quad * 4 + r][ksel * 16 + l16] = f2bf(p2);
                denc_r[r] += p1;
                dens_r[r] += p2;
            }
        }
        __syncthreads();
        // ---- PV: A = P rows (own q-half), B = VV (own d-half), K=32 in one step ----
        bf16x8 aPc = *(const bf16x8*)&P_lds[0][qsel * 16 + l16][quad * 8];
        bf16x8 aPs = *(const bf16x8*)&P_lds[1][qsel * 16 + l16][quad * 8];
        #pragma unroll
        for (int t = 0; t < 8; ++t) {
            int row = t * 16 + l16;               // d mod 128
            int col = ksel * 32 + quad * 8;       // d-half x key-chunk
            bf16x8 bV  = *(const bf16x8*)&VV_c[row][col];
            bf16x8 bVF = *(const bf16x8*)&VV_s[row][col];
            acc_c[t] = __builtin_amdgcn_mfma_f32_16x16x32_bf16(aPc, bV,  acc_c[t], 0, 0, 0);
            acc_s[t] = __builtin_amdgcn_mfma_f32_16x16x32_bf16(aPs, bVF, acc_s[t], 0, 0, 0);
        }
    }

    // ---- denominators: reduce over 16 key-lanes, combine k-halves via LDS ----
    #pragma unroll
    for (int r = 0; r < 4; ++r) {
        #pragma unroll
        for (int m = 1; m < 16; m <<= 1) {
            denc_r[r] += __shfl_xor(denc_r[r], m, 64);
            dens_r[r] += __shfl_xor(dens_r[r], m, 64);
        }
    }
    __syncthreads();  // all PV reads of P done; safe to alias
    float* denbuf = (float*)P_lds;  // [2 branch][2 ksel][32 q]
    if (l16 == 0) {
        #pragma unroll
        for (int r = 0; r < 4; ++r) {
            int q32 = qsel * 16 + quad * 4 + r;
            denbuf[ksel * 32 + q32]      = denc_r[r];
            denbuf[64 + ksel * 32 + q32] = dens_r[r];
        }
    }
    __syncthreads();
    #pragma unroll
    for (int r = 0; r < 4; ++r) {
        int q32 = qsel * 16 + quad * 4 + r;
        float rc = 1.f / (denbuf[q32] + denbuf[32 + q32]);
        float rs = 1.f / (denbuf[64 + q32] + denbuf[96 + q32]);
        // PV C-layout: col=l16 -> d = ksel*128 + t*16 + l16 ; row=quad*4+r -> q
        float* orow = out + (size_t)(q0 + q32) * DM + ksel * 128 + l16;
        #pragma unroll
        for (int t = 0; t < 8; ++t)
            orow[t * 16] = acc_c[t][r] * rc + acc_s[t][r] * rs;
    }
}

extern "C" void kernel_launch(void* const* d_in, const int* in_sizes, int n_in,
                              void* d_out, int out_size, void* d_ws, size_t ws_size,
                              hipStream_t stream)
{
    const float* x      = (const float*)d_in[0];
    const float* ch_mem = (const float*)d_in[1];
    const float* ch_wq  = (const float*)d_in[2];
    const float* ch_wk  = (const float*)d_in[3];
    const float* ch_wv  = (const float*)d_in[4];
    const float* sp_mem = (const float*)d_in[5];
    const float* sp_wq  = (const float*)d_in[6];
    const float* sp_wk  = (const float*)d_in[7];
    const float* sp_wv  = (const float*)d_in[8];
    float* out = (float*)d_out;

    ushort* Qb   = (ushort*)d_ws;                 // [12544][256]
    ushort* QFb  = Qb   + (size_t)NBQ * DM;
    ushort* Kb   = QFb  + (size_t)NBQ * DM;       // [2048][256]
    ushort* KFb  = Kb   + (size_t)MM * DM;
    ushort* Vtb  = KFb  + (size_t)MM * DM;        // [256][2048] transposed
    ushort* VFtb = Vtb  + (size_t)MM * DM;
    float*  qm   = (float*)(VFtb + (size_t)MM * DM);
    float*  qv   = qm + NBQ;
    float*  km   = qv + NBQ;
    float*  kv   = km + MM;

    dim3 blk(256);
    gemm_proj_all<<<dim3(1040), blk, 0, stream>>>(
        x, ch_mem, ch_wq, ch_wk, ch_wv, sp_mem, sp_wq, sp_wk, sp_wv,
        Qb, QFb, Kb, KFb, Vtb, VFtb);
    row_stats_all<<<dim3((NBQ + MM) / 4), blk, 0, stream>>>(QFb, KFb, qm, qv, km, kv);
    fused_attn_mfma<<<dim3(NBQ / 32), blk, 0, stream>>>(
        Qb, QFb, Kb, KFb, Vtb, VFtb, qm, qv, km, kv, out);
}

// Round 12
// 278.829 us; speedup vs baseline: 2.7730x; 1.5192x over previous
//
#include <hip/hip_runtime.h>

#define NBQ 12544
#define DM  256
#define MM  2048

typedef __attribute__((ext_vector_type(8)))  __bf16 bf16x8;
typedef __attribute__((ext_vector_type(4)))  float  floatx4;

__device__ __forceinline__ ushort f2bf(float x) {
    unsigned u = __float_as_uint(x);
    u += 0x7fffu + ((u >> 16) & 1u);   // RNE
    return (ushort)(u >> 16);
}
__device__ __forceinline__ float bf2f(ushort h) {
    return __uint_as_float(((unsigned)h) << 16);
}

// async global->LDS DMA, 16 B per lane; LDS dest = wave-uniform base + lane*16
__device__ __forceinline__ void load_lds16(const ushort* g, ushort* l) {
    __builtin_amdgcn_global_load_lds(
        (const __attribute__((address_space(1))) void*)g,
        (__attribute__((address_space(3))) void*)l,
        16, 0, 0);
}

// ---------- projections, weight-pairs folded: each block computes A*W1^T and A*W2^T --
__global__ __launch_bounds__(256) void gemm_proj_all(
    const float* __restrict__ x,      const float* __restrict__ ch_mem,
    const float* __restrict__ ch_wq,  const float* __restrict__ ch_wk,
    const float* __restrict__ ch_wv,  const float* __restrict__ sp_mem,
    const float* __restrict__ sp_wq,  const float* __restrict__ sp_wk,
    const float* __restrict__ sp_wv,
    ushort* __restrict__ Qb,  ushort* __restrict__ QFb,
    ushort* __restrict__ Kb,  ushort* __restrict__ KFb,
    ushort* __restrict__ Vtb, ushort* __restrict__ VFtb)
{
    __shared__ ushort As[64][72];
    __shared__ ushort W1s[64][72];
    __shared__ ushort W2s[64][72];

    int bid = blockIdx.x;
    const float* A; const float* W1; const float* W2;
    ushort* C1; ushort* C2; int nrows, trans2;
    if (bid < 784) {
        A = x; W1 = ch_wq; W2 = sp_wq; C1 = Qb; C2 = QFb; nrows = NBQ; trans2 = 0;
    } else if (bid < 912) {
        A = ch_mem; W1 = ch_wk; W2 = ch_wv; C1 = Kb; C2 = Vtb;
        nrows = MM; trans2 = 1; bid -= 784;
    } else {
        A = sp_mem; W1 = sp_wk; W2 = sp_wv; C1 = KFb; C2 = VFtb;
        nrows = MM; trans2 = 1; bid -= 912;
    }
    const int r0 = (bid >> 2) * 64;
    const int c0 = (bid & 3) * 64;

    const int tid  = threadIdx.x;
    const int wv   = tid >> 6;
    const int lane = tid & 63;
    const int quad = lane >> 4;
    const int l16  = lane & 15;
    const int rw = (wv & 1) * 32;
    const int cw = (wv >> 1) * 32;

    floatx4 acc1[2][2], acc2[2][2];
    #pragma unroll
    for (int i = 0; i < 2; ++i)
        #pragma unroll
        for (int j = 0; j < 2; ++j) {
            acc1[i][j] = (floatx4){0.f, 0.f, 0.f, 0.f};
            acc2[i][j] = (floatx4){0.f, 0.f, 0.f, 0.f};
        }

    for (int d0 = 0; d0 < 256; d0 += 64) {
        __syncthreads();
        #pragma unroll
        for (int it = 0; it < 4; ++it) {
            int idx = tid + it * 256;
            int r = idx >> 4, c4 = (idx & 15) * 4;
            float4 a4 = *(const float4*)(A  + (size_t)(r0 + r) * 256 + d0 + c4);
            float4 w14 = *(const float4*)(W1 + (size_t)(c0 + r) * 256 + d0 + c4);
            float4 w24 = *(const float4*)(W2 + (size_t)(c0 + r) * 256 + d0 + c4);
            ushort4 ab, w1b, w2b;
            ab.x = f2bf(a4.x);  ab.y = f2bf(a4.y);  ab.z = f2bf(a4.z);  ab.w = f2bf(a4.w);
            w1b.x = f2bf(w14.x); w1b.y = f2bf(w14.y); w1b.z = f2bf(w14.z); w1b.w = f2bf(w14.w);
            w2b.x = f2bf(w24.x); w2b.y = f2bf(w24.y); w2b.z = f2bf(w24.z); w2b.w = f2bf(w24.w);
            *(ushort4*)&As[r][c4]  = ab;
            *(ushort4*)&W1s[r][c4] = w1b;
            *(ushort4*)&W2s[r][c4] = w2b;
        }
        __syncthreads();
        #pragma unroll
        for (int kk = 0; kk < 64; kk += 32) {
            bf16x8 aA0 = *(const bf16x8*)&As[rw + l16][kk + quad * 8];
            bf16x8 aA1 = *(const bf16x8*)&As[rw + 16 + l16][kk + quad * 8];
            bf16x8 b10 = *(const bf16x8*)&W1s[cw + l16][kk + quad * 8];
            bf16x8 b11 = *(const bf16x8*)&W1s[cw + 16 + l16][kk + quad * 8];
            bf16x8 b20 = *(const bf16x8*)&W2s[cw + l16][kk + quad * 8];
            bf16x8 b21 = *(const bf16x8*)&W2s[cw + 16 + l16][kk + quad * 8];
            acc1[0][0] = __builtin_amdgcn_mfma_f32_16x16x32_bf16(aA0, b10, acc1[0][0], 0, 0, 0);
            acc1[0][1] = __builtin_amdgcn_mfma_f32_16x16x32_bf16(aA0, b11, acc1[0][1], 0, 0, 0);
            acc1[1][0] = __builtin_amdgcn_mfma_f32_16x16x32_bf16(aA1, b10, acc1[1][0], 0, 0, 0);
            acc1[1][1] = __builtin_amdgcn_mfma_f32_16x16x32_bf16(aA1, b11, acc1[1][1], 0, 0, 0);
            acc2[0][0] = __builtin_amdgcn_mfma_f32_16x16x32_bf16(aA0, b20, acc2[0][0], 0, 0, 0);
            acc2[0][1] = __builtin_amdgcn_mfma_f32_16x16x32_bf16(aA0, b21, acc2[0][1], 0, 0, 0);
            acc2[1][0] = __builtin_amdgcn_mfma_f32_16x16x32_bf16(aA1, b20, acc2[1][0], 0, 0, 0);
            acc2[1][1] = __builtin_amdgcn_mfma_f32_16x16x32_bf16(aA1, b21, acc2[1][1], 0, 0, 0);
        }
    }

    #pragma unroll
    for (int ag = 0; ag < 2; ++ag)
        #pragma unroll
        for (int cg = 0; cg < 2; ++cg)
            #pragma unroll
            for (int i = 0; i < 4; ++i)
                C1[(size_t)(r0 + rw + ag * 16 + quad * 4 + i) * 256
                   + c0 + cw + cg * 16 + l16] = f2bf(acc1[ag][cg][i]);

    if (!trans2) {
        #pragma unroll
        for (int ag = 0; ag < 2; ++ag)
            #pragma unroll
            for (int cg = 0; cg < 2; ++cg)
                #pragma unroll
                for (int i = 0; i < 4; ++i)
                    C2[(size_t)(r0 + rw + ag * 16 + quad * 4 + i) * 256
                       + c0 + cw + cg * 16 + l16] = f2bf(acc2[ag][cg][i]);
    } else {
        __syncthreads();
        #pragma unroll
        for (int ag = 0; ag < 2; ++ag)
            #pragma unroll
            for (int cg = 0; cg < 2; ++cg)
                #pragma unroll
                for (int i = 0; i < 4; ++i)
                    W2s[cw + cg * 16 + l16][rw + ag * 16 + quad * 4 + i] = f2bf(acc2[ag][cg][i]);
        __syncthreads();
        const int col = tid >> 2;
        const int seg = (tid & 3) * 16;
        #pragma unroll
        for (int j = 0; j < 2; ++j)
            *(uint4*)(C2 + (size_t)(c0 + col) * nrows + r0 + seg + j * 8) =
                *(const uint4*)&W2s[col][seg + j * 8];
    }
}

// ---------------- row stats (QF rows then KF rows), one launch ----------------
__global__ __launch_bounds__(256) void row_stats_all(
    const ushort* __restrict__ QFb, const ushort* __restrict__ KFb,
    float* __restrict__ qm, float* __restrict__ qv,
    float* __restrict__ km, float* __restrict__ kv)
{
    const int rt   = blockIdx.x * 4 + (threadIdx.x >> 6);
    const int lane = threadIdx.x & 63;
    const ushort* X; float* mean; float* var; int row;
    if (rt < NBQ) { X = QFb; mean = qm; var = qv; row = rt; }
    else          { X = KFb; mean = km; var = kv; row = rt - NBQ; }
    ushort4 u = *(const ushort4*)(X + (size_t)row * 256 + lane * 4);
    float a = bf2f(u.x), b = bf2f(u.y), c = bf2f(u.z), d = bf2f(u.w);
    float s  = a + b + c + d;
    float ss = a * a + b * b + c * c + d * d;
    #pragma unroll
    for (int off = 32; off > 0; off >>= 1) {
        s  += __shfl_down(s, off);
        ss += __shfl_down(ss, off);
    }
    if (lane == 0) {
        float m = s * (1.f / 256.f);
        mean[row] = m;
        var[row]  = (ss - 256.f * m * m) * (1.f / 255.f);
    }
}

// ---------------- fused dual attention: r9 structure + global_load_lds staging ------
// Block: 32 queries, 4 waves, BOTH branches. Wave w: qsel=w&1, ksel=w>>1.
// K/KF/Vt/VFt staged via 16B global_load_lds DMA (no VGPR round-trip, no ds_writes);
// unpadded LDS tiles with XOR column swizzle on the GLOBAL source side:
//   LDS[r][c] = SRC[r][c ^ (8*(r&3))]
// Read side: crd = quad*8 ^ 8*(l16&3) is a per-lane constant -> all B-frag reads
// keep immediate-offset ds_read_b128 form (zero extra hot-loop VALU).
__global__ __launch_bounds__(256, 2) void fused_attn_mfma(
    const ushort* __restrict__ Qb,  const ushort* __restrict__ QFb,
    const ushort* __restrict__ Kb,  const ushort* __restrict__ KFb,
    const ushort* __restrict__ Vtb, const ushort* __restrict__ VFtb,
    const float* __restrict__ qm_, const float* __restrict__ qv_,
    const float* __restrict__ km_, const float* __restrict__ kv_,
    float* __restrict__ out)
{
    __shared__ ushort K_lds[32][256];    // unpadded (DMA lane-linear), XOR-swizzled cols
    __shared__ ushort KF_lds[32][256];
    __shared__ ushort Vt_lds[256][32];
    __shared__ ushort VFt_lds[256][32];
    __shared__ ushort P_lds[2][32][36];  // 72B stride (r9-proven)
    // total LDS = 4*16384 + 4608 = 70144 B -> 2 blocks/CU

    const int tid  = threadIdx.x;
    const int wv   = tid >> 6;
    const int lane = tid & 63;
    const int quad = lane >> 4;
    const int l16  = lane & 15;
    const int qsel = wv & 1;
    const int ksel = wv >> 1;
    const int q0   = blockIdx.x * 32;

    // staging source coordinates (per lane)
    const int hk      = lane >> 5;                               // K row parity in instr
    const int kc_even = ((lane & 31) * 8) ^ (8 * hk);            // j even: r&3 = hk
    const int kc_odd  = ((lane & 31) * 8) ^ (8 * ((2 + hk) & 3));// j odd:  r&3 = 2+hk
    const int vrl     = lane >> 2;                               // Vt row in instr
    const int vc      = ((lane & 3) * 8) ^ (8 * (vrl & 3));
    // read-side swizzled chunk (per-lane constant)
    const int crd = (quad * 8) ^ (8 * (l16 & 3));

    // Q A-fragments in registers for the whole key loop
    bf16x8 aQ[8], aQF[8];
    {
        const ushort* qp  = Qb  + (size_t)(q0 + qsel * 16 + l16) * DM + quad * 8;
        const ushort* qfp = QFb + (size_t)(q0 + qsel * 16 + l16) * DM + quad * 8;
        #pragma unroll
        for (int s = 0; s < 8; ++s) {
            aQ[s]  = *(const bf16x8*)(qp  + s * 32);
            aQF[s] = *(const bf16x8*)(qfp + s * 32);
        }
    }
    float qmv[4], qvv[4];
    #pragma unroll
    for (int r = 0; r < 4; ++r) {
        int qg = q0 + qsel * 16 + quad * 4 + r;
        qmv[r] = qm_[qg]; qvv[r] = qv_[qg];
    }

    floatx4 acc_c[8], acc_s[8];
    #pragma unroll
    for (int t = 0; t < 8; ++t) {
        acc_c[t] = (floatx4){0.f, 0.f, 0.f, 0.f};
        acc_s[t] = (floatx4){0.f, 0.f, 0.f, 0.f};
    }
    float denc_r[4] = {0.f, 0.f, 0.f, 0.f};
    float dens_r[4] = {0.f, 0.f, 0.f, 0.f};

    for (int kt = 0; kt < MM; kt += 32) {
        __syncthreads();  // previous tile's LDS fully consumed
        // DMA staging: wave w -> K/KF rows [w*8, w*8+8), Vt/VFt d-rows [w*64, w*64+64)
        #pragma unroll
        for (int j = 0; j < 4; ++j) {
            const int rb = wv * 8 + 2 * j;                 // K LDS row base (uniform)
            const int kc = (j & 1) ? kc_odd : kc_even;
            load_lds16(Kb  + (size_t)(kt + rb + hk) * DM + kc, &K_lds[rb][0]);
            load_lds16(KFb + (size_t)(kt + rb + hk) * DM + kc, &KF_lds[rb][0]);
            const int db = wv * 64 + j * 16;               // Vt LDS row base (uniform)
            load_lds16(Vtb  + (size_t)(db + vrl) * MM + kt + vc, &Vt_lds[db][0]);
            load_lds16(VFtb + (size_t)(db + vrl) * MM + kt + vc, &VFt_lds[db][0]);
        }
        __syncthreads();

        // ---- scores: 16q x 16k per wave, both branches ----
        floatx4 sc = (floatx4){0.f, 0.f, 0.f, 0.f};
        floatx4 sd = (floatx4){0.f, 0.f, 0.f, 0.f};
        #pragma unroll
        for (int s = 0; s < 8; ++s) {
            bf16x8 bK  = *(const bf16x8*)&K_lds[ksel * 16 + l16][s * 32 + crd];
            bf16x8 bKF = *(const bf16x8*)&KF_lds[ksel * 16 + l16][s * 32 + crd];
            sc = __builtin_amdgcn_mfma_f32_16x16x32_bf16(aQ[s],  bK,  sc, 0, 0, 0);
            sd = __builtin_amdgcn_mfma_f32_16x16x32_bf16(aQF[s], bKF, sd, 0, 0, 0);
        }
        // ---- epilogue: exp(score/16), SSIM -> P (bf16), denominator partials ----
        {
            float kmv = km_[kt + ksel * 16 + l16];
            float kvv = kv_[kt + ksel * 16 + l16];
            #pragma unroll
            for (int r = 0; r < 4; ++r) {
                float p1  = __expf(sc[r] * 0.0625f);
                float mp  = qmv[r] * kmv;
                float cov = (sd[r] - 256.f * mp) * (1.f / 255.f);
                float num = (2.f * mp + 0.01f) * (2.f * cov + 0.03f);
                float den = (qmv[r] * qmv[r] + kmv * kmv + 0.01f) * (qvv[r] + kvv + 0.03f);
                float p2  = __expf(num / (den + 1e-8f));
                P_lds[0][qsel * 16 + quad * 4 + r][ksel * 16 + l16] = f2bf(p1);
                P_lds[1][qsel * 16 + quad * 4 + r][ksel * 16 + l16] = f2bf(p2);
                denc_r[r] += p1;
                dens_r[r] += p2;
            }
        }
        __syncthreads();
        // ---- PV: A = P rows (own q-half), B = Vt (own d-half), K=32 in one step ----
        bf16x8 aPc = *(const bf16x8*)&P_lds[0][qsel * 16 + l16][quad * 8];
        bf16x8 aPs = *(const bf16x8*)&P_lds[1][qsel * 16 + l16][quad * 8];
        #pragma unroll
        for (int t = 0; t < 8; ++t) {
            int d0 = ksel * 128 + t * 16;
            bf16x8 bV  = *(const bf16x8*)&Vt_lds[d0 + l16][crd];
            bf16x8 bVF = *(const bf16x8*)&VFt_lds[d0 + l16][crd];
            acc_c[t] = __builtin_amdgcn_mfma_f32_16x16x32_bf16(aPc, bV,  acc_c[t], 0, 0, 0);
            acc_s[t] = __builtin_amdgcn_mfma_f32_16x16x32_bf16(aPs, bVF, acc_s[t], 0, 0, 0);
        }
    }

    // ---- denominators: reduce over 16 key-lanes, combine k-halves via LDS ----
    #pragma unroll
    for (int r = 0; r < 4; ++r) {
        #pragma unroll
        for (int m = 1; m < 16; m <<= 1) {
            denc_r[r] += __shfl_xor(denc_r[r], m, 64);
            dens_r[r] += __shfl_xor(dens_r[r], m, 64);
        }
    }
    __syncthreads();  // all PV reads of P done; safe to alias
    float* denbuf = (float*)P_lds;  // [2 branch][2 ksel][32 q]
    if (l16 == 0) {
        #pragma unroll
        for (int r = 0; r < 4; ++r) {
            int q32 = qsel * 16 + quad * 4 + r;
            denbuf[ksel * 32 + q32]      = denc_r[r];
            denbuf[64 + ksel * 32 + q32] = dens_r[r];
        }
    }
    __syncthreads();
    #pragma unroll
    for (int r = 0; r < 4; ++r) {
        int q32 = qsel * 16 + quad * 4 + r;
        float rc = 1.f / (denbuf[q32] + denbuf[32 + q32]);
        float rs = 1.f / (denbuf[64 + q32] + denbuf[96 + q32]);
        float* orow = out + (size_t)(q0 + q32) * DM + ksel * 128 + l16;
        #pragma unroll
        for (int t = 0; t < 8; ++t)
            orow[t * 16] = acc_c[t][r] * rc + acc_s[t][r] * rs;
    }
}

extern "C" void kernel_launch(void* const* d_in, const int* in_sizes, int n_in,
                              void* d_out, int out_size, void* d_ws, size_t ws_size,
                              hipStream_t stream)
{
    const float* x      = (const float*)d_in[0];
    const float* ch_mem = (const float*)d_in[1];
    const float* ch_wq  = (const float*)d_in[2];
    const float* ch_wk  = (const float*)d_in[3];
    const float* ch_wv  = (const float*)d_in[4];
    const float* sp_mem = (const float*)d_in[5];
    const float* sp_wq  = (const float*)d_in[6];
    const float* sp_wk  = (const float*)d_in[7];
    const float* sp_wv  = (const float*)d_in[8];
    float* out = (float*)d_out;

    ushort* Qb   = (ushort*)d_ws;                 // [12544][256]
    ushort* QFb  = Qb   + (size_t)NBQ * DM;
    ushort* Kb   = QFb  + (size_t)NBQ * DM;       // [2048][256]
    ushort* KFb  = Kb   + (size_t)MM * DM;
    ushort* Vtb  = KFb  + (size_t)MM * DM;        // [256][2048] transposed
    ushort* VFtb = Vtb  + (size_t)MM * DM;
    float*  qm   = (float*)(VFtb + (size_t)MM * DM);
    float*  qv   = qm + NBQ;
    float*  km   = qv + NBQ;
    float*  kv   = km + MM;

    dim3 blk(256);
    gemm_proj_all<<<dim3(1040), blk, 0, stream>>>(
        x, ch_mem, ch_wq, ch_wk, ch_wv, sp_mem, sp_wq, sp_wk, sp_wv,
        Qb, QFb, Kb, KFb, Vtb, VFtb);
    row_stats_all<<<dim3((NBQ + MM) / 4), blk, 0, stream>>>(QFb, KFb, qm, qv, km, kv);
    fused_attn_mfma<<<dim3(NBQ / 32), blk, 0, stream>>>(
        Qb, QFb, Kb, KFb, Vtb, VFtb, qm, qv, km, kv, out);
}

// Round 13
// 269.168 us; speedup vs baseline: 2.8725x; 1.0359x over previous
//
#include <hip/hip_runtime.h>

#define NBQ 12544
#define DM  256
#define MM  2048

typedef __attribute__((ext_vector_type(8)))  __bf16 bf16x8;
typedef __attribute__((ext_vector_type(4)))  float  floatx4;

__device__ __forceinline__ ushort f2bf(float x) {
    unsigned u = __float_as_uint(x);
    u += 0x7fffu + ((u >> 16) & 1u);   // RNE
    return (ushort)(u >> 16);
}
__device__ __forceinline__ float bf2f(ushort h) {
    return __uint_as_float(((unsigned)h) << 16);
}

// ---------- projections, weight-pairs folded (r11/r12-proven) ----------
__global__ __launch_bounds__(256) void gemm_proj_all(
    const float* __restrict__ x,      const float* __restrict__ ch_mem,
    const float* __restrict__ ch_wq,  const float* __restrict__ ch_wk,
    const float* __restrict__ ch_wv,  const float* __restrict__ sp_mem,
    const float* __restrict__ sp_wq,  const float* __restrict__ sp_wk,
    const float* __restrict__ sp_wv,
    ushort* __restrict__ Qb,  ushort* __restrict__ QFb,
    ushort* __restrict__ Kb,  ushort* __restrict__ KFb,
    ushort* __restrict__ Vtb, ushort* __restrict__ VFtb)
{
    __shared__ ushort As[64][72];
    __shared__ ushort W1s[64][72];
    __shared__ ushort W2s[64][72];

    int bid = blockIdx.x;
    const float* A; const float* W1; const float* W2;
    ushort* C1; ushort* C2; int nrows, trans2;
    if (bid < 784) {
        A = x; W1 = ch_wq; W2 = sp_wq; C1 = Qb; C2 = QFb; nrows = NBQ; trans2 = 0;
    } else if (bid < 912) {
        A = ch_mem; W1 = ch_wk; W2 = ch_wv; C1 = Kb; C2 = Vtb;
        nrows = MM; trans2 = 1; bid -= 784;
    } else {
        A = sp_mem; W1 = sp_wk; W2 = sp_wv; C1 = KFb; C2 = VFtb;
        nrows = MM; trans2 = 1; bid -= 912;
    }
    const int r0 = (bid >> 2) * 64;
    const int c0 = (bid & 3) * 64;

    const int tid  = threadIdx.x;
    const int wv   = tid >> 6;
    const int lane = tid & 63;
    const int quad = lane >> 4;
    const int l16  = lane & 15;
    const int rw = (wv & 1) * 32;
    const int cw = (wv >> 1) * 32;

    floatx4 acc1[2][2], acc2[2][2];
    #pragma unroll
    for (int i = 0; i < 2; ++i)
        #pragma unroll
        for (int j = 0; j < 2; ++j) {
            acc1[i][j] = (floatx4){0.f, 0.f, 0.f, 0.f};
            acc2[i][j] = (floatx4){0.f, 0.f, 0.f, 0.f};
        }

    for (int d0 = 0; d0 < 256; d0 += 64) {
        __syncthreads();
        #pragma unroll
        for (int it = 0; it < 4; ++it) {
            int idx = tid + it * 256;
            int r = idx >> 4, c4 = (idx & 15) * 4;
            float4 a4 = *(const float4*)(A  + (size_t)(r0 + r) * 256 + d0 + c4);
            float4 w14 = *(const float4*)(W1 + (size_t)(c0 + r) * 256 + d0 + c4);
            float4 w24 = *(const float4*)(W2 + (size_t)(c0 + r) * 256 + d0 + c4);
            ushort4 ab, w1b, w2b;
            ab.x = f2bf(a4.x);  ab.y = f2bf(a4.y);  ab.z = f2bf(a4.z);  ab.w = f2bf(a4.w);
            w1b.x = f2bf(w14.x); w1b.y = f2bf(w14.y); w1b.z = f2bf(w14.z); w1b.w = f2bf(w14.w);
            w2b.x = f2bf(w24.x); w2b.y = f2bf(w24.y); w2b.z = f2bf(w24.z); w2b.w = f2bf(w24.w);
            *(ushort4*)&As[r][c4]  = ab;
            *(ushort4*)&W1s[r][c4] = w1b;
            *(ushort4*)&W2s[r][c4] = w2b;
        }
        __syncthreads();
        #pragma unroll
        for (int kk = 0; kk < 64; kk += 32) {
            bf16x8 aA0 = *(const bf16x8*)&As[rw + l16][kk + quad * 8];
            bf16x8 aA1 = *(const bf16x8*)&As[rw + 16 + l16][kk + quad * 8];
            bf16x8 b10 = *(const bf16x8*)&W1s[cw + l16][kk + quad * 8];
            bf16x8 b11 = *(const bf16x8*)&W1s[cw + 16 + l16][kk + quad * 8];
            bf16x8 b20 = *(const bf16x8*)&W2s[cw + l16][kk + quad * 8];
            bf16x8 b21 = *(const bf16x8*)&W2s[cw + 16 + l16][kk + quad * 8];
            acc1[0][0] = __builtin_amdgcn_mfma_f32_16x16x32_bf16(aA0, b10, acc1[0][0], 0, 0, 0);
            acc1[0][1] = __builtin_amdgcn_mfma_f32_16x16x32_bf16(aA0, b11, acc1[0][1], 0, 0, 0);
            acc1[1][0] = __builtin_amdgcn_mfma_f32_16x16x32_bf16(aA1, b10, acc1[1][0], 0, 0, 0);
            acc1[1][1] = __builtin_amdgcn_mfma_f32_16x16x32_bf16(aA1, b11, acc1[1][1], 0, 0, 0);
            acc2[0][0] = __builtin_amdgcn_mfma_f32_16x16x32_bf16(aA0, b20, acc2[0][0], 0, 0, 0);
            acc2[0][1] = __builtin_amdgcn_mfma_f32_16x16x32_bf16(aA0, b21, acc2[0][1], 0, 0, 0);
            acc2[1][0] = __builtin_amdgcn_mfma_f32_16x16x32_bf16(aA1, b20, acc2[1][0], 0, 0, 0);
            acc2[1][1] = __builtin_amdgcn_mfma_f32_16x16x32_bf16(aA1, b21, acc2[1][1], 0, 0, 0);
        }
    }

    #pragma unroll
    for (int ag = 0; ag < 2; ++ag)
        #pragma unroll
        for (int cg = 0; cg < 2; ++cg)
            #pragma unroll
            for (int i = 0; i < 4; ++i)
                C1[(size_t)(r0 + rw + ag * 16 + quad * 4 + i) * 256
                   + c0 + cw + cg * 16 + l16] = f2bf(acc1[ag][cg][i]);

    if (!trans2) {
        #pragma unroll
        for (int ag = 0; ag < 2; ++ag)
            #pragma unroll
            for (int cg = 0; cg < 2; ++cg)
                #pragma unroll
                for (int i = 0; i < 4; ++i)
                    C2[(size_t)(r0 + rw + ag * 16 + quad * 4 + i) * 256
                       + c0 + cw + cg * 16 + l16] = f2bf(acc2[ag][cg][i]);
    } else {
        __syncthreads();
        #pragma unroll
        for (int ag = 0; ag < 2; ++ag)
            #pragma unroll
            for (int cg = 0; cg < 2; ++cg)
                #pragma unroll
                for (int i = 0; i < 4; ++i)
                    W2s[cw + cg * 16 + l16][rw + ag * 16 + quad * 4 + i] = f2bf(acc2[ag][cg][i]);
        __syncthreads();
        const int col = tid >> 2;
        const int seg = (tid & 3) * 16;
        #pragma unroll
        for (int j = 0; j < 2; ++j)
            *(uint4*)(C2 + (size_t)(c0 + col) * nrows + r0 + seg + j * 8) =
                *(const uint4*)&W2s[col][seg + j * 8];
    }
}

// ---------------- KF row stats only (Q stats now inline in fused) ----------------
__global__ __launch_bounds__(256) void row_stats_kf(
    const ushort* __restrict__ KFb, float* __restrict__ km, float* __restrict__ kv)
{
    const int row  = blockIdx.x * 4 + (threadIdx.x >> 6);
    const int lane = threadIdx.x & 63;
    ushort4 u = *(const ushort4*)(KFb + (size_t)row * 256 + lane * 4);
    float a = bf2f(u.x), b = bf2f(u.y), c = bf2f(u.z), d = bf2f(u.w);
    float s  = a + b + c + d;
    float ss = a * a + b * b + c * c + d * d;
    #pragma unroll
    for (int off = 32; off > 0; off >>= 1) {
        s  += __shfl_down(s, off);
        ss += __shfl_down(ss, off);
    }
    if (lane == 0) {
        float m = s * (1.f / 256.f);
        km[row] = m;
        kv[row] = (ss - 256.f * m * m) * (1.f / 255.f);
    }
}

// ---------------- fused dual attention: S^T scores, P in registers ----------------
// Block: 32 queries, 4 waves. Wave roles: qsel = wv&1, branch = wv>>1 (0=ch, 1=sp).
// Scores computed TRANSPOSED (A=K, B=Q): C col=l16=q, row=quad*4+r=key-within-subtile.
// K LDS rows are PERMUTED: LDS row l holds key 8*(l>>2 mod 4) + 4*(l>=16) + (l&3),
// so the epilogue's 8 p-values per lane are exactly A-frag slots k=quad*8+j with
// key=quad*8+j -> P feeds PV directly from registers; PV B-read = plain Vt[d][quad*8]
// b128 (r9-identical). 2 barriers/tile (was 3); den self-contained per wave.
// Branch combine via LDS reuse of the dead Vt buffers (no atomics).
__global__ __launch_bounds__(256, 2) void fused_attn_st(
    const ushort* __restrict__ Qb,  const ushort* __restrict__ QFb,
    const ushort* __restrict__ Kb,  const ushort* __restrict__ KFb,
    const ushort* __restrict__ Vtb, const ushort* __restrict__ VFtb,
    const float* __restrict__ km_, const float* __restrict__ kv_,
    float* __restrict__ out)
{
    __shared__ ushort SM[37376];                       // 74752 B -> 2 blocks/CU
    ushort (*K_lds)[264]  = (ushort(*)[264])(SM);          // 32 x 264 (permuted rows)
    ushort (*KF_lds)[264] = (ushort(*)[264])(SM + 8448);
    ushort (*Vt_lds)[40]  = (ushort(*)[40])(SM + 16896);   // 256 x 40
    ushort (*VFt_lds)[40] = (ushort(*)[40])(SM + 27136);
    float* combuf = (float*)(SM + 16896);              // 32 KB, aliases Vt after loop

    const int tid  = threadIdx.x;
    const int wv   = tid >> 6;
    const int lane = tid & 63;
    const int quad = lane >> 4;
    const int l16  = lane & 15;
    const int qsel = wv & 1;
    const int br   = wv >> 1;          // 0 = channel, 1 = spatial
    const int q0   = blockIdx.x * 32;

    const ushort* qsrc = br ? QFb : Qb;
    bf16x8 aQ[8];
    {
        const ushort* qp = qsrc + (size_t)(q0 + qsel * 16 + l16) * DM + quad * 8;
        #pragma unroll
        for (int s = 0; s < 8; ++s) aQ[s] = *(const bf16x8*)(qp + s * 32);
    }

    // inline Q-stats for spatial waves (row = q0 + qsel*16 + l16, from aQ regs)
    float qmv = 0.f, qvv = 0.f;
    if (br) {
        float sum = 0.f, ss = 0.f;
        #pragma unroll
        for (int s = 0; s < 8; ++s)
            #pragma unroll
            for (int j = 0; j < 8; ++j) {
                float v = (float)aQ[s][j];
                sum += v; ss += v * v;
            }
        sum += __shfl_xor(sum, 16, 64); sum += __shfl_xor(sum, 32, 64);
        ss  += __shfl_xor(ss, 16, 64);  ss  += __shfl_xor(ss, 32, 64);
        qmv = sum * (1.f / 256.f);
        qvv = (ss - 256.f * qmv * qmv) * (1.f / 255.f);
    }

    floatx4 acc[16];
    #pragma unroll
    for (int t = 0; t < 16; ++t) acc[t] = (floatx4){0.f, 0.f, 0.f, 0.f};
    float den = 0.f;

    for (int kt = 0; kt < MM; kt += 32) {
        __syncthreads();  // previous tile's LDS fully consumed
        // stage K/KF with row permutation: global row r -> LDS row pr
        #pragma unroll
        for (int it = 0; it < 4; ++it) {
            int idx = tid + it * 256;
            int r = idx >> 5, c8 = (idx & 31) * 8;
            int pr = ((r & 4) << 2) | ((r >> 3) << 2) | (r & 3);
            *(uint4*)&K_lds[pr][c8]  = *(const uint4*)(Kb  + (size_t)(kt + r) * DM + c8);
            *(uint4*)&KF_lds[pr][c8] = *(const uint4*)(KFb + (size_t)(kt + r) * DM + c8);
        }
        // stage Vt/VFt (256 dims x 32 keys)
        #pragma unroll
        for (int it = 0; it < 4; ++it) {
            int idx = tid + it * 256;
            int d = idx >> 2, kc = (idx & 3) * 8;
            *(uint4*)&Vt_lds[d][kc]  = *(const uint4*)(Vtb  + (size_t)d * MM + kt + kc);
            *(uint4*)&VFt_lds[d][kc] = *(const uint4*)(VFtb + (size_t)d * MM + kt + kc);
        }
        __syncthreads();

        // ---- S^T scores: A = K rows (2 subtiles), B = Q regs, K=256 ----
        floatx4 S0 = (floatx4){0.f, 0.f, 0.f, 0.f};
        floatx4 S1 = (floatx4){0.f, 0.f, 0.f, 0.f};
        const ushort (*Ksrc)[264] = br ? KF_lds : K_lds;
        #pragma unroll
        for (int s = 0; s < 8; ++s) {
            bf16x8 aK0 = *(const bf16x8*)&Ksrc[l16][s * 32 + quad * 8];
            bf16x8 aK1 = *(const bf16x8*)&Ksrc[16 + l16][s * 32 + quad * 8];
            S0 = __builtin_amdgcn_mfma_f32_16x16x32_bf16(aK0, aQ[s], S0, 0, 0, 0);
            S1 = __builtin_amdgcn_mfma_f32_16x16x32_bf16(aK1, aQ[s], S1, 0, 0, 0);
        }
        // lane holds S^T[key = 8*quad + 4*sub + r][q = qsel*16 + l16], sub0=S0, sub1=S1

        // ---- epilogue -> p[8] in regs (A-frag slot j = 4*sub + r, key = 8*quad+j) ----
        float p[8];
        if (!br) {
            #pragma unroll
            for (int r = 0; r < 4; ++r) {
                p[r]     = __expf(S0[r] * 0.0625f);
                p[4 + r] = __expf(S1[r] * 0.0625f);
            }
        } else {
            floatx4 km0 = *(const floatx4*)(km_ + kt + 8 * quad);
            floatx4 km1 = *(const floatx4*)(km_ + kt + 8 * quad + 4);
            floatx4 kv0 = *(const floatx4*)(kv_ + kt + 8 * quad);
            floatx4 kv1 = *(const floatx4*)(kv_ + kt + 8 * quad + 4);
            #pragma unroll
            for (int r = 0; r < 4; ++r) {
                {
                    float mp  = qmv * km0[r];
                    float cov = (S0[r] - 256.f * mp) * (1.f / 255.f);
                    float num = (2.f * mp + 0.01f) * (2.f * cov + 0.03f);
                    float dn  = (qmv * qmv + km0[r] * km0[r] + 0.01f) * (qvv + kv0[r] + 0.03f);
                    p[r] = __expf(num / (dn + 1e-8f));
                }
                {
                    float mp  = qmv * km1[r];
                    float cov = (S1[r] - 256.f * mp) * (1.f / 255.f);
                    float num = (2.f * mp + 0.01f) * (2.f * cov + 0.03f);
                    float dn  = (qmv * qmv + km1[r] * km1[r] + 0.01f) * (qvv + kv1[r] + 0.03f);
                    p[4 + r] = __expf(num / (dn + 1e-8f));
                }
            }
        }
        union { ushort u[8]; bf16x8 v; } ap;
        #pragma unroll
        for (int j = 0; j < 8; ++j) {
            den += p[j];
            ap.u[j] = f2bf(p[j]);
        }

        // ---- PV: A = P regs, B = Vt[d][quad*8] b128 (r9-identical), K=32 ----
        const ushort (*Vsrc)[40] = br ? VFt_lds : Vt_lds;
        #pragma unroll
        for (int t = 0; t < 16; ++t) {
            bf16x8 bV = *(const bf16x8*)&Vsrc[t * 16 + l16][quad * 8];
            acc[t] = __builtin_amdgcn_mfma_f32_16x16x32_bf16(ap.v, bV, acc[t], 0, 0, 0);
        }
    }

    // ---- den: reduce across quads (each lane covered keys 8*quad+0..7 per tile) ----
    den += __shfl_xor(den, 16, 64);
    den += __shfl_xor(den, 32, 64);
    // den now holds full denominator for q = qsel*16 + l16; broadcast to C-layout rows
    float rdn[4];
    #pragma unroll
    for (int r = 0; r < 4; ++r)
        rdn[r] = 1.f / __shfl(den, quad * 4 + r, 64);

    __syncthreads();  // last tile's Vt reads done; safe to alias combuf
    if (br) {
        #pragma unroll
        for (int t = 0; t < 16; ++t)
            #pragma unroll
            for (int r = 0; r < 4; ++r)
                combuf[(qsel * 16 + quad * 4 + r) * 256 + t * 16 + l16] = acc[t][r] * rdn[r];
    }
    __syncthreads();
    if (!br) {
        #pragma unroll
        for (int t = 0; t < 16; ++t)
            #pragma unroll
            for (int r = 0; r < 4; ++r) {
                int ql = qsel * 16 + quad * 4 + r;
                out[(size_t)(q0 + ql) * DM + t * 16 + l16] =
                    acc[t][r] * rdn[r] + combuf[ql * 256 + t * 16 + l16];
            }
    }
}

extern "C" void kernel_launch(void* const* d_in, const int* in_sizes, int n_in,
                              void* d_out, int out_size, void* d_ws, size_t ws_size,
                              hipStream_t stream)
{
    const float* x      = (const float*)d_in[0];
    const float* ch_mem = (const float*)d_in[1];
    const float* ch_wq  = (const float*)d_in[2];
    const float* ch_wk  = (const float*)d_in[3];
    const float* ch_wv  = (const float*)d_in[4];
    const float* sp_mem = (const float*)d_in[5];
    const float* sp_wq  = (const float*)d_in[6];
    const float* sp_wk  = (const float*)d_in[7];
    const float* sp_wv  = (const float*)d_in[8];
    float* out = (float*)d_out;

    ushort* Qb   = (ushort*)d_ws;                 // [12544][256]
    ushort* QFb  = Qb   + (size_t)NBQ * DM;
    ushort* Kb   = QFb  + (size_t)NBQ * DM;       // [2048][256]
    ushort* KFb  = Kb   + (size_t)MM * DM;
    ushort* Vtb  = KFb  + (size_t)MM * DM;        // [256][2048] transposed
    ushort* VFtb = Vtb  + (size_t)MM * DM;
    float*  km   = (float*)(VFtb + (size_t)MM * DM);
    float*  kv   = km + MM;

    dim3 blk(256);
    gemm_proj_all<<<dim3(1040), blk, 0, stream>>>(
        x, ch_mem, ch_wq, ch_wk, ch_wv, sp_mem, sp_wq, sp_wk, sp_wv,
        Qb, QFb, Kb, KFb, Vtb, VFtb);
    row_stats_kf<<<dim3(MM / 4), blk, 0, stream>>>(KFb, km, kv);
    fused_attn_st<<<dim3(NBQ / 32), blk, 0, stream>>>(
        Qb, QFb, Kb, KFb, Vtb, VFtb, km, kv, out);
}